// Round 3
// baseline (107.696 us; speedup 1.0000x reference)
//
#include <hip/hip_runtime.h>

namespace {

constexpr int R     = 4;           // radius = int(4*1 + 0.5)
constexpr int TSX   = 64;          // output tile width
constexpr int TSY   = 64;          // output tile height
constexpr int HR    = TSY + 2 * R; // 72 hbuf rows (output rows + vertical halo)
constexpr int HSTR  = TSX + 4;     // 68-float LDS row stride (272 B, 16B-aligned, 4-bank skew)
constexpr int IMG_H = 512;
constexpr int IMG_W = 512;

__device__ __forceinline__ int clampi(int v, int lo, int hi) {
    return v < lo ? lo : (v > hi ? hi : v);
}

__global__ __launch_bounds__(256, 8)
void gauss_blur_kernel(const float* __restrict__ in, float* __restrict__ out) {
    const float KW[9] = {
        1.3383062e-4f, 4.4318616e-3f, 5.3990966e-2f, 2.4197144e-1f,
        3.9894347e-1f, 2.4197144e-1f, 5.3990966e-2f, 4.4318616e-3f,
        1.3383062e-4f};

    __shared__ float hbuf[HR * HSTR];  // 72 x 64 horizontal-pass result (19584 B)

    const int tid = threadIdx.x;
    const int b   = blockIdx.z;
    const int ty0 = blockIdx.y * TSY;
    const int tx0 = blockIdx.x * TSX;

    const float* __restrict__ inb = in + (size_t)b * IMG_H * IMG_W;

    // ---- phase 1: horizontal 9-tap pass, global -> LDS ----
    // 72 rows x 16 float4-producers per row; inputs read straight from global
    // (3 overlapping coalesced float4 loads; overlap is L1/L2-resident).
    for (int i = tid; i < HR * (TSX / 4); i += 256) {
        int r  = i >> 4;          // hbuf row 0..71
        int j  = i & 15;          // float4 index within row
        int gy = clampi(ty0 - R + r, 0, IMG_H - 1);
        const float* rp = inb + gy * IMG_W;
        int xo = tx0 + 4 * j;     // first output x of this float4

        float w[12];              // inputs [xo-4, xo+8)
        #pragma unroll
        for (int v = 0; v < 3; ++v) {
            int a = xo - 4 + 4 * v;
            float4 val;
            if (a >= 0 && a <= IMG_W - 4) {
                val = *reinterpret_cast<const float4*>(rp + a);
            } else {  // only first/last x-tiles
                val.x = rp[clampi(a + 0, 0, IMG_W - 1)];
                val.y = rp[clampi(a + 1, 0, IMG_W - 1)];
                val.z = rp[clampi(a + 2, 0, IMG_W - 1)];
                val.w = rp[clampi(a + 3, 0, IMG_W - 1)];
            }
            w[4 * v + 0] = val.x; w[4 * v + 1] = val.y;
            w[4 * v + 2] = val.z; w[4 * v + 3] = val.w;
        }

        float a0 = 0.f, a1 = 0.f, a2 = 0.f, a3 = 0.f;
        #pragma unroll
        for (int t = 0; t < 9; ++t) {
            a0 = fmaf(KW[t], w[t + 0], a0);
            a1 = fmaf(KW[t], w[t + 1], a1);
            a2 = fmaf(KW[t], w[t + 2], a2);
            a3 = fmaf(KW[t], w[t + 3], a3);
        }
        float4 o = {a0, a1, a2, a3};
        *reinterpret_cast<float4*>(&hbuf[r * HSTR + 4 * j]) = o;
    }
    __syncthreads();

    // ---- phase 2: vertical 9-tap pass in registers ----
    // Each thread owns a 4-wide x 4-tall output patch: streams 12 hbuf rows,
    // accumulates into 4 float4 accs (3 LDS reads per output).
    const int px  = tid & 15;     // x-patch 0..15
    const int py  = tid >> 4;     // y-patch 0..15
    const int lx  = 4 * px;
    const int oy0 = 4 * py;       // first output row (hbuf-relative)

    float4 acc[4] = {{0,0,0,0},{0,0,0,0},{0,0,0,0},{0,0,0,0}};
    #pragma unroll
    for (int t = 0; t < 12; ++t) {
        float4 h = *reinterpret_cast<const float4*>(&hbuf[(oy0 + t) * HSTR + lx]);
        #pragma unroll
        for (int rr = 0; rr < 4; ++rr) {
            int k = t - rr;
            if (k >= 0 && k < 9) {
                acc[rr].x = fmaf(KW[k], h.x, acc[rr].x);
                acc[rr].y = fmaf(KW[k], h.y, acc[rr].y);
                acc[rr].z = fmaf(KW[k], h.z, acc[rr].z);
                acc[rr].w = fmaf(KW[k], h.w, acc[rr].w);
            }
        }
    }

    float* __restrict__ outb = out + (size_t)b * IMG_H * IMG_W;
    #pragma unroll
    for (int rr = 0; rr < 4; ++rr) {
        *reinterpret_cast<float4*>(&outb[(ty0 + oy0 + rr) * IMG_W + tx0 + lx]) = acc[rr];
    }
}

}  // namespace

extern "C" void kernel_launch(void* const* d_in, const int* in_sizes, int n_in,
                              void* d_out, int out_size, void* d_ws, size_t ws_size,
                              hipStream_t stream) {
    const float* x = (const float*)d_in[0];
    float* out = (float*)d_out;

    const int batch = in_sizes[0] / (IMG_H * IMG_W);  // 128

    dim3 grid(IMG_W / TSX, IMG_H / TSY, batch);       // (8, 8, 128)
    gauss_blur_kernel<<<grid, 256, 0, stream>>>(x, out);
}

// Round 4
// 105.672 us; speedup vs baseline: 1.0192x; 1.0192x over previous
//
#include <hip/hip_runtime.h>

namespace {

constexpr int R     = 4;           // radius = int(4*1 + 0.5)
constexpr int TSX   = 64;          // output tile width
constexpr int TSY   = 64;          // output tile height
constexpr int HR    = TSY + 2 * R; // 72 hbuf rows
constexpr int HSTR  = TSX + 4;     // 68-float LDS row stride
constexpr int IMG_H = 512;
constexpr int IMG_W = 512;
constexpr int WPR   = TSX / 4;     // 16 float4 work items per row
constexpr int NW    = HR * WPR;    // 1152 phase-1 work items

__device__ __forceinline__ int clampi(int v, int lo, int hi) {
    return v < lo ? lo : (v > hi ? hi : v);
}

__device__ __forceinline__ void hpass_store(const float* __restrict__ KW,
                                            float* __restrict__ hbuf,
                                            int r, int j,
                                            float4 v0, float4 v1, float4 v2) {
    float w[12] = {v0.x, v0.y, v0.z, v0.w,
                   v1.x, v1.y, v1.z, v1.w,
                   v2.x, v2.y, v2.z, v2.w};
    float a0 = 0.f, a1 = 0.f, a2 = 0.f, a3 = 0.f;
    #pragma unroll
    for (int t = 0; t < 9; ++t) {
        a0 = fmaf(KW[t], w[t + 0], a0);
        a1 = fmaf(KW[t], w[t + 1], a1);
        a2 = fmaf(KW[t], w[t + 2], a2);
        a3 = fmaf(KW[t], w[t + 3], a3);
    }
    float4 o = {a0, a1, a2, a3};
    *reinterpret_cast<float4*>(&hbuf[r * HSTR + 4 * j]) = o;
}

__global__ __launch_bounds__(256)
void gauss_blur_kernel(const float* __restrict__ in, float* __restrict__ out) {
    const float KW[9] = {
        1.3383062e-4f, 4.4318616e-3f, 5.3990966e-2f, 2.4197144e-1f,
        3.9894347e-1f, 2.4197144e-1f, 5.3990966e-2f, 4.4318616e-3f,
        1.3383062e-4f};

    __shared__ float hbuf[HR * HSTR];  // 72 x 64 h-pass result (19584 B)

    const int tid = threadIdx.x;
    const int b   = blockIdx.z;
    const int ty0 = blockIdx.y * TSY;
    const int tx0 = blockIdx.x * TSX;

    const float* __restrict__ inb = in + (size_t)b * IMG_H * IMG_W;

    // ---- phase 1: horizontal 9-tap pass, global -> LDS ----
    const bool interior = (tx0 - R >= 0) && (tx0 + TSX + 2 * R <= IMG_W);

    if (interior) {
        // Hot path (6/8 block columns): all loads unconditional, two work
        // items per iteration -> up to 6 float4 loads in flight per wave.
        for (int base = tid; base < NW; base += 512) {
            const int i0 = base;
            const int r0 = i0 >> 4, j0 = i0 & 15;
            const float* p0 = inb + (size_t)clampi(ty0 - R + r0, 0, IMG_H - 1) * IMG_W
                                  + (tx0 - R + 4 * j0);
            float4 u0 = *reinterpret_cast<const float4*>(p0);
            float4 u1 = *reinterpret_cast<const float4*>(p0 + 4);
            float4 u2 = *reinterpret_cast<const float4*>(p0 + 8);

            const int i1 = base + 256;
            const bool has1 = i1 < NW;
            int r1 = 0, j1 = 0;
            float4 v0 = {}, v1 = {}, v2 = {};
            if (has1) {
                r1 = i1 >> 4; j1 = i1 & 15;
                const float* p1 = inb + (size_t)clampi(ty0 - R + r1, 0, IMG_H - 1) * IMG_W
                                      + (tx0 - R + 4 * j1);
                v0 = *reinterpret_cast<const float4*>(p1);
                v1 = *reinterpret_cast<const float4*>(p1 + 4);
                v2 = *reinterpret_cast<const float4*>(p1 + 8);
            }

            hpass_store(KW, hbuf, r0, j0, u0, u1, u2);
            if (has1) hpass_store(KW, hbuf, r1, j1, v0, v1, v2);
        }
    } else {
        // Edge block columns: per-element clamped loads.
        for (int i = tid; i < NW; i += 256) {
            const int r = i >> 4, j = i & 15;
            const int gy = clampi(ty0 - R + r, 0, IMG_H - 1);
            const float* rp = inb + (size_t)gy * IMG_W;
            const int xo = tx0 + 4 * j;
            float4 q[3];
            #pragma unroll
            for (int v = 0; v < 3; ++v) {
                const int a = xo - R + 4 * v;
                q[v].x = rp[clampi(a + 0, 0, IMG_W - 1)];
                q[v].y = rp[clampi(a + 1, 0, IMG_W - 1)];
                q[v].z = rp[clampi(a + 2, 0, IMG_W - 1)];
                q[v].w = rp[clampi(a + 3, 0, IMG_W - 1)];
            }
            hpass_store(KW, hbuf, r, j, q[0], q[1], q[2]);
        }
    }
    __syncthreads();

    // ---- phase 2: vertical 9-tap pass in registers ----
    const int px  = tid & 15;
    const int py  = tid >> 4;
    const int lx  = 4 * px;
    const int oy0 = 4 * py;

    float4 acc[4] = {{0,0,0,0},{0,0,0,0},{0,0,0,0},{0,0,0,0}};
    #pragma unroll
    for (int t = 0; t < 12; ++t) {
        float4 h = *reinterpret_cast<const float4*>(&hbuf[(oy0 + t) * HSTR + lx]);
        #pragma unroll
        for (int rr = 0; rr < 4; ++rr) {
            int k = t - rr;
            if (k >= 0 && k < 9) {
                acc[rr].x = fmaf(KW[k], h.x, acc[rr].x);
                acc[rr].y = fmaf(KW[k], h.y, acc[rr].y);
                acc[rr].z = fmaf(KW[k], h.z, acc[rr].z);
                acc[rr].w = fmaf(KW[k], h.w, acc[rr].w);
            }
        }
    }

    float* __restrict__ outb = out + (size_t)b * IMG_H * IMG_W;
    #pragma unroll
    for (int rr = 0; rr < 4; ++rr) {
        *reinterpret_cast<float4*>(&outb[(ty0 + oy0 + rr) * IMG_W + tx0 + lx]) = acc[rr];
    }
}

}  // namespace

extern "C" void kernel_launch(void* const* d_in, const int* in_sizes, int n_in,
                              void* d_out, int out_size, void* d_ws, size_t ws_size,
                              hipStream_t stream) {
    const float* x = (const float*)d_in[0];
    float* out = (float*)d_out;

    const int batch = in_sizes[0] / (IMG_H * IMG_W);  // 128

    dim3 grid(IMG_W / TSX, IMG_H / TSY, batch);       // (8, 8, 128)
    gauss_blur_kernel<<<grid, 256, 0, stream>>>(x, out);
}

// Round 5
// 64.344 us; speedup vs baseline: 1.6738x; 1.6423x over previous
//
#include <hip/hip_runtime.h>

namespace {

constexpr int R     = 4;            // radius = int(4*1 + 0.5)
constexpr int TSX   = 64;           // output tile width
constexpr int TSY   = 32;           // output tile height
constexpr int RAWH  = TSY + 2 * R;  // 40 staged rows
constexpr int RSTR  = 76;           // s_raw stride (floats)
constexpr int HSTR  = 68;           // s_h stride (floats)
constexpr int IMG_H = 512;
constexpr int IMG_W = 512;
constexpr int NMAIN = RAWH * (TSX / 4);  // 640 main stage items (raw cols 0..63)
constexpr int NHALO = RAWH * 2;          // 80 halo stage items (raw cols 64..71)
constexpr int NHP   = RAWH * (TSX / 4);  // 640 h-pass items

__device__ __forceinline__ int clampi(int v, int lo, int hi) {
    return v < lo ? lo : (v > hi ? hi : v);
}

__global__ __launch_bounds__(256)
void gauss_blur_kernel(const float* __restrict__ in, float* __restrict__ out) {
    const float KW[9] = {
        1.3383062e-4f, 4.4318616e-3f, 5.3990966e-2f, 2.4197144e-1f,
        3.9894347e-1f, 2.4197144e-1f, 5.3990966e-2f, 4.4318616e-3f,
        1.3383062e-4f};

    __shared__ float s_raw[RAWH * RSTR];  // 40 x 72 raw input (12160 B)
    __shared__ float s_h  [RAWH * HSTR];  // 40 x 64 h-pass result (10880 B)

    const int tid = threadIdx.x;
    const int b   = blockIdx.z;
    const int ty0 = blockIdx.y * TSY;
    const int tx0 = blockIdx.x * TSX;

    const float* __restrict__ inb = in + (size_t)b * IMG_H * IMG_W;

    // ---- phase 1: stage raw 72x40 tile (edge-clamped), 1 float4 per item ----
    // raw col c == global x (tx0 - 4 + c); main = cols 0..63, halo = cols 64..71.
    const bool interior = (tx0 - R >= 0) && (tx0 + TSX - R + 4 + 3 < IMG_W);

    if (interior) {
        for (int i = tid; i < NMAIN; i += 256) {
            const int r = i >> 4, c = i & 15;
            const int gy = clampi(ty0 - R + r, 0, IMG_H - 1);
            float4 v = *reinterpret_cast<const float4*>(
                inb + (size_t)gy * IMG_W + (tx0 - R + 4 * c));
            *reinterpret_cast<float4*>(&s_raw[r * RSTR + 4 * c]) = v;
        }
        if (tid < NHALO) {
            const int r = tid >> 1, h = tid & 1;
            const int gy = clampi(ty0 - R + r, 0, IMG_H - 1);
            float4 v = *reinterpret_cast<const float4*>(
                inb + (size_t)gy * IMG_W + (tx0 + TSX - R + 4 * h));
            *reinterpret_cast<float4*>(&s_raw[r * RSTR + TSX + 4 * h]) = v;
        }
    } else {
        for (int i = tid; i < NMAIN + NHALO; i += 256) {
            int r, cc;
            if (i < NMAIN) { r = i >> 4; cc = 4 * (i & 15); }
            else           { int k = i - NMAIN; r = k >> 1; cc = TSX + 4 * (k & 1); }
            const int gy = clampi(ty0 - R + r, 0, IMG_H - 1);
            const float* rp = inb + (size_t)gy * IMG_W;
            const int gx = tx0 - R + cc;
            float4 v;
            v.x = rp[clampi(gx + 0, 0, IMG_W - 1)];
            v.y = rp[clampi(gx + 1, 0, IMG_W - 1)];
            v.z = rp[clampi(gx + 2, 0, IMG_W - 1)];
            v.w = rp[clampi(gx + 3, 0, IMG_W - 1)];
            *reinterpret_cast<float4*>(&s_raw[r * RSTR + cc]) = v;
        }
    }
    __syncthreads();

    // ---- phase 2: horizontal 9-tap pass, s_raw -> s_h ----
    for (int i = tid; i < NHP; i += 256) {
        const int r = i >> 4, j = i & 15;
        const float* rp = &s_raw[r * RSTR + 4 * j];
        float4 a  = *reinterpret_cast<const float4*>(rp);
        float4 bq = *reinterpret_cast<const float4*>(rp + 4);
        float4 cq = *reinterpret_cast<const float4*>(rp + 8);
        float w[12] = {a.x, a.y, a.z, a.w, bq.x, bq.y, bq.z, bq.w,
                       cq.x, cq.y, cq.z, cq.w};
        float a0 = 0.f, a1 = 0.f, a2 = 0.f, a3 = 0.f;
        #pragma unroll
        for (int t = 0; t < 9; ++t) {
            a0 = fmaf(KW[t], w[t + 0], a0);
            a1 = fmaf(KW[t], w[t + 1], a1);
            a2 = fmaf(KW[t], w[t + 2], a2);
            a3 = fmaf(KW[t], w[t + 3], a3);
        }
        float4 o = {a0, a1, a2, a3};
        *reinterpret_cast<float4*>(&s_h[r * HSTR + 4 * j]) = o;
    }
    __syncthreads();

    // ---- phase 3: vertical 9-tap in registers, 4-wide x 2-tall patches ----
    const int px  = tid & 15;
    const int py  = tid >> 4;
    const int lx  = 4 * px;
    const int oy0 = 2 * py;   // output rows oy0, oy0+1 (tile-relative)

    float4 acc0 = {0.f, 0.f, 0.f, 0.f};
    float4 acc1 = {0.f, 0.f, 0.f, 0.f};
    #pragma unroll
    for (int t = 0; t < 10; ++t) {
        float4 h = *reinterpret_cast<const float4*>(&s_h[(oy0 + t) * HSTR + lx]);
        if (t < 9) {
            acc0.x = fmaf(KW[t], h.x, acc0.x);
            acc0.y = fmaf(KW[t], h.y, acc0.y);
            acc0.z = fmaf(KW[t], h.z, acc0.z);
            acc0.w = fmaf(KW[t], h.w, acc0.w);
        }
        if (t >= 1) {
            acc1.x = fmaf(KW[t - 1], h.x, acc1.x);
            acc1.y = fmaf(KW[t - 1], h.y, acc1.y);
            acc1.z = fmaf(KW[t - 1], h.z, acc1.z);
            acc1.w = fmaf(KW[t - 1], h.w, acc1.w);
        }
    }

    float* __restrict__ outb = out + (size_t)b * IMG_H * IMG_W;
    *reinterpret_cast<float4*>(&outb[(size_t)(ty0 + oy0) * IMG_W + tx0 + lx]) = acc0;
    *reinterpret_cast<float4*>(&outb[(size_t)(ty0 + oy0 + 1) * IMG_W + tx0 + lx]) = acc1;
}

}  // namespace

extern "C" void kernel_launch(void* const* d_in, const int* in_sizes, int n_in,
                              void* d_out, int out_size, void* d_ws, size_t ws_size,
                              hipStream_t stream) {
    const float* x = (const float*)d_in[0];
    float* out = (float*)d_out;

    const int batch = in_sizes[0] / (IMG_H * IMG_W);  // 128

    dim3 grid(IMG_W / TSX, IMG_H / TSY, batch);       // (8, 16, 128)
    gauss_blur_kernel<<<grid, 256, 0, stream>>>(x, out);
}

// Round 6
// 62.605 us; speedup vs baseline: 1.7202x; 1.0278x over previous
//
#include <hip/hip_runtime.h>
#include <stdint.h>

namespace {

constexpr int R     = 4;             // radius = int(4*1 + 0.5)
constexpr int TSX   = 64;            // output tile width
constexpr int TSY   = 32;            // output tile height
constexpr int RAWH  = TSY + 2 * R;   // 40 staged rows
constexpr int RF4   = 19;            // float4 per raw row (76 floats, 72 valid)
constexpr int RSTRF = RF4 * 4;       // 76-float raw row stride
constexpr int NRAW4 = RAWH * RF4;    // 760 float4 slots
constexpr int NCHUNK = 12;           // ceil(760/64) chunks of 64 float4 (1024 B)
constexpr int HSTR  = 68;            // s_h stride (floats)
constexpr int IMG_H = 512;
constexpr int IMG_W = 512;
constexpr int NHP   = RAWH * (TSX / 4);  // 640 h-pass items

__device__ __forceinline__ int clampi(int v, int lo, int hi) {
    return v < lo ? lo : (v > hi ? hi : v);
}

__global__ __launch_bounds__(256)
void gauss_blur_kernel(const float* __restrict__ in, float* __restrict__ out) {
    const float KW[9] = {
        1.3383062e-4f, 4.4318616e-3f, 5.3990966e-2f, 2.4197144e-1f,
        3.9894347e-1f, 2.4197144e-1f, 5.3990966e-2f, 4.4318616e-3f,
        1.3383062e-4f};

    __shared__ float s_raw[NCHUNK * 256];  // 12288 B, lane-linear [row(76f) x 40]
    __shared__ float s_h  [RAWH * HSTR];   // 10880 B

    const int tid  = threadIdx.x;
    const int lane = tid & 63;
    const int wave = tid >> 6;
    const int b    = blockIdx.z;
    const int ty0  = blockIdx.y * TSY;
    const int tx0  = blockIdx.x * TSX;

    const float* __restrict__ inb = in + (size_t)b * IMG_H * IMG_W;

    // ---- phase 1: stage raw 72x40 tile into LDS ----
    const bool x_interior = (blockIdx.x >= 1) && (blockIdx.x + 1 < IMG_W / TSX);

    if (x_interior) {
        // Direct global->LDS DMA: each wave issues 3 chunk loads back-to-back
        // (async, no VGPR round-trip, no per-load vmcnt stall). LDS dest is
        // wave-uniform base + lane*16; per-lane SOURCE address encodes the
        // (row,col) layout and the y edge-clamp.
        #pragma unroll
        for (int k = 0; k < 3; ++k) {
            const int q  = wave * 3 + k;          // chunk 0..11
            const int f  = (q << 6) | lane;       // flat float4 slot
            const int ru = (int)((unsigned)f / 19u);
            const int c  = f - 19 * ru;           // f4 col 0..18 (col 18 = pad)
            const int r  = ru > RAWH - 1 ? RAWH - 1 : ru;  // only chunk 11 tail
            const int gy = clampi(ty0 - R + r, 0, IMG_H - 1);
            const float* src = inb + (size_t)gy * IMG_W + (tx0 - R + 4 * c);
            __builtin_amdgcn_global_load_lds(
                (const __attribute__((address_space(1))) uint32_t*)src,
                (__attribute__((address_space(3))) uint32_t*)(s_raw + (q << 8)),
                16, 0, 0);
        }
    } else {
        // Edge block columns (x=0,7): per-element clamped loads, same layout.
        for (int i = tid; i < NRAW4; i += 256) {
            const int r  = (int)((unsigned)i / 19u);
            const int c  = i - 19 * r;
            const int gy = clampi(ty0 - R + r, 0, IMG_H - 1);
            const float* rp = inb + (size_t)gy * IMG_W;
            const int gx = tx0 - R + 4 * c;
            float4 v;
            v.x = rp[clampi(gx + 0, 0, IMG_W - 1)];
            v.y = rp[clampi(gx + 1, 0, IMG_W - 1)];
            v.z = rp[clampi(gx + 2, 0, IMG_W - 1)];
            v.w = rp[clampi(gx + 3, 0, IMG_W - 1)];
            *reinterpret_cast<float4*>(&s_raw[(r * RF4 + c) * 4]) = v;
        }
    }
    __syncthreads();

    // ---- phase 2: horizontal 9-tap pass, s_raw -> s_h ----
    for (int i = tid; i < NHP; i += 256) {
        const int r = i >> 4, j = i & 15;
        const float* rp = &s_raw[r * RSTRF + 4 * j];
        float4 a  = *reinterpret_cast<const float4*>(rp);
        float4 bq = *reinterpret_cast<const float4*>(rp + 4);
        float4 cq = *reinterpret_cast<const float4*>(rp + 8);
        float w[12] = {a.x, a.y, a.z, a.w, bq.x, bq.y, bq.z, bq.w,
                       cq.x, cq.y, cq.z, cq.w};
        float a0 = 0.f, a1 = 0.f, a2 = 0.f, a3 = 0.f;
        #pragma unroll
        for (int t = 0; t < 9; ++t) {
            a0 = fmaf(KW[t], w[t + 0], a0);
            a1 = fmaf(KW[t], w[t + 1], a1);
            a2 = fmaf(KW[t], w[t + 2], a2);
            a3 = fmaf(KW[t], w[t + 3], a3);
        }
        float4 o = {a0, a1, a2, a3};
        *reinterpret_cast<float4*>(&s_h[r * HSTR + 4 * j]) = o;
    }
    __syncthreads();

    // ---- phase 3: vertical 9-tap in registers, 4-wide x 2-tall patches ----
    const int px  = tid & 15;
    const int py  = tid >> 4;
    const int lx  = 4 * px;
    const int oy0 = 2 * py;

    float4 acc0 = {0.f, 0.f, 0.f, 0.f};
    float4 acc1 = {0.f, 0.f, 0.f, 0.f};
    #pragma unroll
    for (int t = 0; t < 10; ++t) {
        float4 h = *reinterpret_cast<const float4*>(&s_h[(oy0 + t) * HSTR + lx]);
        if (t < 9) {
            acc0.x = fmaf(KW[t], h.x, acc0.x);
            acc0.y = fmaf(KW[t], h.y, acc0.y);
            acc0.z = fmaf(KW[t], h.z, acc0.z);
            acc0.w = fmaf(KW[t], h.w, acc0.w);
        }
        if (t >= 1) {
            acc1.x = fmaf(KW[t - 1], h.x, acc1.x);
            acc1.y = fmaf(KW[t - 1], h.y, acc1.y);
            acc1.z = fmaf(KW[t - 1], h.z, acc1.z);
            acc1.w = fmaf(KW[t - 1], h.w, acc1.w);
        }
    }

    float* __restrict__ outb = out + (size_t)b * IMG_H * IMG_W;
    *reinterpret_cast<float4*>(&outb[(size_t)(ty0 + oy0) * IMG_W + tx0 + lx]) = acc0;
    *reinterpret_cast<float4*>(&outb[(size_t)(ty0 + oy0 + 1) * IMG_W + tx0 + lx]) = acc1;
}

}  // namespace

extern "C" void kernel_launch(void* const* d_in, const int* in_sizes, int n_in,
                              void* d_out, int out_size, void* d_ws, size_t ws_size,
                              hipStream_t stream) {
    const float* x = (const float*)d_in[0];
    float* out = (float*)d_out;

    const int batch = in_sizes[0] / (IMG_H * IMG_W);  // 128

    dim3 grid(IMG_W / TSX, IMG_H / TSY, batch);       // (8, 16, 128)
    gauss_blur_kernel<<<grid, 256, 0, stream>>>(x, out);
}